// Round 2
// baseline (86.782 us; speedup 1.0000x reference)
//
#include <hip/hip_runtime.h>

// GeometryAwareCostVolume — MI355X (gfx950), R2
//
// vs R1 (85 us): R1 was latency-bound — whole grid co-resident (15 waves/CU),
// per-thread chain of 40 taps / 80 conflicted ds_read_b128 / 72 strided stores.
// Changes:
//  * 2x blocks (split row halves), 4x threads per output row: thread=(w,level)
//    -> per-thread chain 10 taps / 18 stores; ~2 scheduling rounds of ~6
//    blocks/CU instead of one fully-resident round.
//  * bin split into two 16B arrays (pA=c0..3, pB=c4..7): tap ds_read_b128 start
//    quads go 4 classes -> 8 classes (conflict ~2x -> ~1.4x); staging writes
//    (c-fastest index) are conflict-free.
//  * f1 fragment loaded straight from global (L1/L2 cached, coalesced).
// Algebra unchanged: geo==feat (write twice); integer dx taps -> shared lerp
// fraction, 10 bins/level; pool-before-dot (cost volume never materialized).

namespace {
constexpr int B_ = 2, C_ = 64, H_ = 80, W_ = 160;
constexpr int G_ = 8, GC_ = 8, L_ = 4, K_ = 9, R_ = 4;
constexpr int HW_ = H_ * W_;
constexpr int NCH_ = 2 * L_ * G_ * K_;  // 576
constexpr int TPB = 320;                // 5 waves; thread=(w_local in 80, level in 4)
constexpr int NBINS = 160 + 80 + 40 + 20;  // 300 pooled bins, all levels
constexpr float INV_SQRT_GC = 0.35355339059327373f;
}

__global__ __launch_bounds__(TPB, 5) void gacv_kernel(
    const float* __restrict__ fmap1, const float* __restrict__ fmap2,
    const float* __restrict__ coords, float* __restrict__ out) {
  // Bin c0..3 in pA, c4..7 in pB; entries 16B so tap reads are b128 with 8
  // possible start-quads (bin%8) instead of 4.
  __shared__ __align__(16) float pA[NBINS * 4];
  __shared__ __align__(16) float pB[NBINS * 4];

  const int tid = threadIdx.x;
  const int bid = blockIdx.x;
  const int half = bid & 1;
  const int rid = bid >> 1;  // (b*G + g)*H + h
  const int h = rid % H_;
  const int bg = rid / H_;
  const int g = bg % G_;
  const int b = bg / G_;

  // ---- stage level-0 row, c-fastest so LDS writes are consecutive (no conflict)
  const float* f2base = fmap2 + (size_t)(b * C_ + g * GC_) * HW_ + h * W_;
  for (int idx = tid; idx < W_ * GC_; idx += TPB) {
    int c = idx & 7;
    int v = idx >> 3;
    float val = f2base[c * HW_ + v];
    if (c < 4) pA[v * 4 + c] = val;
    else       pB[v * 4 + (c - 4)] = val;
  }
  __syncthreads();
  // ---- hierarchical pair-mean pyramid (matches reference association)
  for (int idx = tid; idx < 80 * 4; idx += TPB) {
    int t = idx >> 2, c = idx & 3;
    pA[(160 + t) * 4 + c] = 0.5f * (pA[(2 * t) * 4 + c] + pA[(2 * t + 1) * 4 + c]);
    pB[(160 + t) * 4 + c] = 0.5f * (pB[(2 * t) * 4 + c] + pB[(2 * t + 1) * 4 + c]);
  }
  __syncthreads();
  for (int idx = tid; idx < 40 * 4; idx += TPB) {
    int t = idx >> 2, c = idx & 3;
    pA[(240 + t) * 4 + c] = 0.5f * (pA[(160 + 2 * t) * 4 + c] + pA[(160 + 2 * t + 1) * 4 + c]);
    pB[(240 + t) * 4 + c] = 0.5f * (pB[(160 + 2 * t) * 4 + c] + pB[(160 + 2 * t + 1) * 4 + c]);
  }
  __syncthreads();
  for (int idx = tid; idx < 20 * 4; idx += TPB) {
    int t = idx >> 2, c = idx & 3;
    pA[(280 + t) * 4 + c] = 0.5f * (pA[(240 + 2 * t) * 4 + c] + pA[(240 + 2 * t + 1) * 4 + c]);
    pB[(280 + t) * 4 + c] = 0.5f * (pB[(240 + 2 * t) * 4 + c] + pB[(240 + 2 * t + 1) * 4 + c]);
  }
  __syncthreads();

  // ---- compute: thread = (w_local, level); all 320 threads active
  const int w_local = tid % 80;
  const int lvl = tid / 80;
  const int w = half * 80 + w_local;

  float f1v[GC_];
  const float* f1base = fmap1 + (size_t)(b * C_ + g * GC_) * HW_ + h * W_ + w;
#pragma unroll
  for (int c = 0; c < GC_; ++c) f1v[c] = f1base[c * HW_] * INV_SQRT_GC;

  const float cx = coords[(b * H_ + h) * W_ + w];
  const float xl = ldexpf(cx, -lvl);            // cx / 2^lvl, exact
  const int Wl = W_ >> lvl;
  const int ofs = (lvl == 0) ? 0 : (lvl == 1) ? 160 : (lvl == 2) ? 240 : 280;
  const float F = floorf(xl);
  const int fi = (int)F;
  const float w1 = xl - F;  // shared lerp fraction (dx taps are integers)
  const float w0 = 1.0f - w1;

  float T[2 * R_ + 2];  // pooled-bin dots fi-4 .. fi+5, zero outside [0,Wl)
#pragma unroll
  for (int j = 0; j < 2 * R_ + 2; ++j) {
    int t = fi - R_ + j;
    int tc = min(max(t, 0), Wl - 1);
    const float4 a = *(const float4*)(pA + (ofs + tc) * 4);
    const float4 q = *(const float4*)(pB + (ofs + tc) * 4);
    float s = f1v[0] * a.x + f1v[1] * a.y + f1v[2] * a.z + f1v[3] * a.w +
              f1v[4] * q.x + f1v[5] * q.y + f1v[6] * q.z + f1v[7] * q.w;
    T[j] = (t == tc) ? s : 0.0f;  // mask out-of-range taps (reference semantics)
  }

  float* outb = out + (size_t)b * NCH_ * HW_ + h * W_ + w;
  const int chBase = lvl * (2 * G_ * K_) + g * K_;
#pragma unroll
  for (int k = 0; k < K_; ++k) {
    float val = w0 * T[k] + w1 * T[k + 1];
    outb[(size_t)(chBase + k) * HW_] = val;             // feat copy
    outb[(size_t)(chBase + G_ * K_ + k) * HW_] = val;   // geo copy (identical)
  }
}

extern "C" void kernel_launch(void* const* d_in, const int* in_sizes, int n_in,
                              void* d_out, int out_size, void* d_ws, size_t ws_size,
                              hipStream_t stream) {
  const float* fmap1 = (const float*)d_in[0];
  const float* fmap2 = (const float*)d_in[1];
  const float* coords = (const float*)d_in[2];
  float* out = (float*)d_out;
  gacv_kernel<<<dim3(B_ * G_ * H_ * 2), dim3(TPB), 0, stream>>>(fmap1, fmap2, coords, out);
}

// Round 3
// 85.265 us; speedup vs baseline: 1.0178x; 1.0178x over previous
//
#include <hip/hip_runtime.h>
#include <hip/hip_fp16.h>

// GeometryAwareCostVolume — MI355X (gfx950), R3
//
// Model (R2 post-mortem): dur_us carries ~58 us of in-graph harness poison
// (268 MB d_ws fills @ ~6 TB/s dominate top-5); kernel itself ~28 us vs a
// ~12 us HBM floor. Co-limiter: LDS pipe (20 conflicted ds_read_b128 gathers
// per thread + staging transpose).
//
// R3 change: pooled bins live in LDS as 4 planes of __half2 (channel-pair x
// bin). Tap gather = 4 ds_read_b32 at random dword addresses -> ~2 lanes/bank
// avg = conflict-free (2-way is free on gfx950); gather bytes halve. Staging
// is v-fastest (coalesced global reads) AND consecutive-dword LDS writes
// (conflict-free) — no transpose tension. LDS 4.8 KB/block.
// Algebra unchanged: geo==feat (write twice); integer dx -> shared lerp
// fraction, 10 bins/level; pool-before-dot (cost volume never materialized).

namespace {
constexpr int B_ = 2, C_ = 64, H_ = 80, W_ = 160;
constexpr int G_ = 8, GC_ = 8, L_ = 4, K_ = 9, R_ = 4;
constexpr int HW_ = H_ * W_;
constexpr int NCH_ = 2 * L_ * G_ * K_;     // 576
constexpr int TPB = 320;                   // 5 waves; thread=(w_local in 80, level in 4)
constexpr int NBINS = 160 + 80 + 40 + 20;  // 300 bins across levels
constexpr float INV_SQRT_GC = 0.35355339059327373f;
}

__global__ __launch_bounds__(TPB) void gacv_kernel(
    const float* __restrict__ fmap1, const float* __restrict__ fmap2,
    const float* __restrict__ coords, float* __restrict__ out) {
  // plane p holds channels {2p, 2p+1} packed as half2, indexed by bin.
  __shared__ __half2 pln[4][NBINS];

  const int tid = threadIdx.x;
  const int bid = blockIdx.x;
  const int half = bid & 1;
  const int rid = bid >> 1;  // (b*G + g)*H + h
  const int h = rid % H_;
  const int bg = rid / H_;
  const int g = bg % G_;
  const int b = bg / G_;

  // ---- stage level-0 row: v-fastest => coalesced global reads AND
  // consecutive-dword LDS writes (conflict-free).
  const float* f2base = fmap2 + (size_t)(b * C_ + g * GC_) * HW_ + h * W_;
  for (int idx = tid; idx < 4 * W_; idx += TPB) {
    int v = idx % W_;
    int pair = idx / W_;
    float lo = f2base[(2 * pair) * HW_ + v];
    float hi = f2base[(2 * pair + 1) * HW_ + v];
    pln[pair][v] = __floats2half2_rn(lo, hi);
  }
  __syncthreads();
  // ---- hierarchical pair-mean pyramid (matches reference association).
  // Packed fp16 math; reads at stride-2 dwords = 2-way (free), writes seq.
  const __half2 halfc = __float2half2_rn(0.5f);
  {  // level 1: 80 bins x 4 pairs = 320 items (== TPB)
    int t = tid % 80, pair = tid / 80;
    pln[pair][160 + t] = __hmul2(__hadd2(pln[pair][2 * t], pln[pair][2 * t + 1]), halfc);
  }
  __syncthreads();
  if (tid < 160) {  // level 2: 40 x 4
    int t = tid % 40, pair = tid / 40;
    pln[pair][240 + t] = __hmul2(__hadd2(pln[pair][160 + 2 * t], pln[pair][160 + 2 * t + 1]), halfc);
  }
  __syncthreads();
  if (tid < 80) {  // level 3: 20 x 4
    int t = tid % 20, pair = tid / 20;
    pln[pair][280 + t] = __hmul2(__hadd2(pln[pair][240 + 2 * t], pln[pair][240 + 2 * t + 1]), halfc);
  }
  __syncthreads();

  // ---- compute: thread = (w_local, level)
  const int w_local = tid % 80;
  const int lvl = tid / 80;
  const int w = half * 80 + w_local;

  float f1v[GC_];
  const float* f1base = fmap1 + (size_t)(b * C_ + g * GC_) * HW_ + h * W_ + w;
#pragma unroll
  for (int c = 0; c < GC_; ++c) f1v[c] = f1base[c * HW_] * INV_SQRT_GC;

  const float cx = coords[(b * H_ + h) * W_ + w];
  const float xl = ldexpf(cx, -lvl);        // cx / 2^lvl, exact
  const int Wl = W_ >> lvl;
  const int ofs = 320 - (320 >> lvl);       // {0,160,240,280}
  const float F = floorf(xl);
  const int fi = (int)F;
  const float w1 = xl - F;  // shared lerp fraction (dx taps are integers)
  const float w0 = 1.0f - w1;

  float T[2 * R_ + 2];  // pooled-bin dots fi-4 .. fi+5, zero outside [0,Wl)
#pragma unroll
  for (int j = 0; j < 2 * R_ + 2; ++j) {
    int t = fi - R_ + j;
    int tc = min(max(t, 0), Wl - 1);
    int bi = ofs + tc;
    float2 c0 = __half22float2(pln[0][bi]);
    float2 c1 = __half22float2(pln[1][bi]);
    float2 c2 = __half22float2(pln[2][bi]);
    float2 c3 = __half22float2(pln[3][bi]);
    float s = f1v[0] * c0.x + f1v[1] * c0.y + f1v[2] * c1.x + f1v[3] * c1.y +
              f1v[4] * c2.x + f1v[5] * c2.y + f1v[6] * c3.x + f1v[7] * c3.y;
    T[j] = (t == tc) ? s : 0.0f;  // mask out-of-range taps (reference semantics)
  }

  float* outb = out + (size_t)b * NCH_ * HW_ + h * W_ + w;
  const int chBase = lvl * (2 * G_ * K_) + g * K_;
#pragma unroll
  for (int k = 0; k < K_; ++k) {
    float val = w0 * T[k] + w1 * T[k + 1];
    outb[(size_t)(chBase + k) * HW_] = val;            // feat copy
    outb[(size_t)(chBase + G_ * K_ + k) * HW_] = val;  // geo copy (identical)
  }
}

extern "C" void kernel_launch(void* const* d_in, const int* in_sizes, int n_in,
                              void* d_out, int out_size, void* d_ws, size_t ws_size,
                              hipStream_t stream) {
  const float* fmap1 = (const float*)d_in[0];
  const float* fmap2 = (const float*)d_in[1];
  const float* coords = (const float*)d_in[2];
  float* out = (float*)d_out;
  gacv_kernel<<<dim3(B_ * G_ * H_ * 2), dim3(TPB), 0, stream>>>(fmap1, fmap2, coords, out);
}